// Round 5
// baseline (3884.433 us; speedup 1.0000x reference)
//
#include <hip/hip_runtime.h>

// RGCN 3-layer forward, MI355X — fused aggregate-then-transform, edge-parallel.
// Identity: sum_e x[src_e] @ W_r == (sum_e x[src_e]) @ W_r.
// Edges bucket-sorted by (rel, dst_tile_of_64) -> 8*NT contiguous unordered lists,
// one packed int (row<<20|src) per edge. Per layer, ONE kernel: block owns 64 dst
// rows; per relation, 4 waves consume the bucket edge-list EDGE-PARALLEL
// (quarter-wave per edge, 256B coalesced row read, LDS ds_add_f32 accumulate into
// fp32 tile), then MFMA into persistent reg accumulator (A from LDS fp32->bf16,
// B from L2-hot wt). Root r=8 reads A straight from global x. Layer-3 epilogue
// fuses bias + log-softmax (row fits one 16-lane group).
// Round-4 lesson: serial per-row gather = latency-bound (8.9% VALU, 3.9% HBM).

#define DEVI __device__ __forceinline__

typedef __attribute__((ext_vector_type(8))) short bf16x8;
typedef __attribute__((ext_vector_type(4))) float f32x4;

DEVI unsigned short f2b(float f) {
  unsigned int u = __builtin_bit_cast(unsigned int, f);
  unsigned int r = (u + 0x7FFFu + ((u >> 16) & 1u)) >> 16;
  return (unsigned short)r;
}
DEVI float b2f(unsigned short h) {
  unsigned int u = ((unsigned int)h) << 16;
  return __builtin_bit_cast(float, u);
}

// ---------------- bucket sort by key = rel*NT + (dst>>6) ----------------

__global__ void k_zero2(int* __restrict__ cnt, int n) {
  int stride = gridDim.x * blockDim.x;
  for (int i = blockIdx.x * blockDim.x + threadIdx.x; i < n; i += stride) cnt[i] = 0;
}

__global__ void k_hist2(const int* __restrict__ et, const int* __restrict__ edst,
                        int* __restrict__ cnt, int NT, int E) {
  int stride = gridDim.x * blockDim.x;
  for (int i = blockIdx.x * blockDim.x + threadIdx.x; i < E; i += stride)
    atomicAdd(&cnt[(et[i] & 7) * NT + (edst[i] >> 6)], 1);
}

__global__ void k_scan1(const int* __restrict__ cnt, int* __restrict__ offs,
                        int* __restrict__ bsum, int KT) {
  __shared__ int l[256];
  int g = blockIdx.x * 256 + threadIdx.x;
  int v = (g < KT) ? cnt[g] : 0;
  l[threadIdx.x] = v;
  __syncthreads();
  for (int o = 1; o < 256; o <<= 1) {
    int t = (threadIdx.x >= o) ? l[threadIdx.x - o] : 0;
    __syncthreads();
    l[threadIdx.x] += t;
    __syncthreads();
  }
  if (g < KT) offs[g] = l[threadIdx.x] - v;
  if (threadIdx.x == 255) bsum[blockIdx.x] = l[255];
}

__global__ void k_scan2(int* __restrict__ bsum, int nb) {
  __shared__ int l[256];
  __shared__ int carry;
  if (threadIdx.x == 0) carry = 0;
  __syncthreads();
  for (int base = 0; base < nb; base += 256) {
    int g = base + threadIdx.x;
    int v = (g < nb) ? bsum[g] : 0;
    l[threadIdx.x] = v;
    __syncthreads();
    for (int o = 1; o < 256; o <<= 1) {
      int t = (threadIdx.x >= o) ? l[threadIdx.x - o] : 0;
      __syncthreads();
      l[threadIdx.x] += t;
      __syncthreads();
    }
    if (g < nb) bsum[g] = l[threadIdx.x] - v + carry;
    __syncthreads();
    if (threadIdx.x == 0) carry += l[255];
    __syncthreads();
  }
}

__global__ void k_scan3(int* __restrict__ offs, const int* __restrict__ bsum,
                        int* __restrict__ cursor, int KT, int E) {
  int g = blockIdx.x * 256 + threadIdx.x;
  if (g < KT) {
    int v = offs[g] + bsum[blockIdx.x];
    offs[g] = v;
    cursor[g] = v;
  }
  if (g == 0) offs[KT] = E;
}

__global__ void k_fill2(const int* __restrict__ et, const int* __restrict__ esrc,
                        const int* __restrict__ edst, int* __restrict__ cursor,
                        int* __restrict__ packed, int NT, int E) {
  int stride = gridDim.x * blockDim.x;
  for (int i = blockIdx.x * blockDim.x + threadIdx.x; i < E; i += stride) {
    int d = edst[i];
    int key = (et[i] & 7) * NT + (d >> 6);
    int pos = atomicAdd(&cursor[key], 1);
    packed[pos] = ((d & 63) << 20) | esrc[i];
  }
}

// ---------------- weight prep: fp32 [9][128][DOUT] -> bf16 transposed [9][DOUT][128] ----------------

__global__ void wprep_kernel(const float* __restrict__ Wrel, const float* __restrict__ Wroot,
                             unsigned short* __restrict__ wt, int DOUT) {
  int total = 9 * 128 * DOUT;
  int stride = gridDim.x * blockDim.x;
  for (int i = blockIdx.x * blockDim.x + threadIdx.x; i < total; i += stride) {
    int k = i & 127;
    int oo = i >> 7;           // rr*DOUT + o
    int o = oo % DOUT;
    int rr = oo / DOUT;
    float v = (rr < 8) ? Wrel[((size_t)rr * 128 + k) * DOUT + o]
                       : Wroot[(size_t)k * DOUT + o];
    wt[i] = f2b(v);
  }
}

// ---------------- fused layer ----------------
// out = act( x@Wroot + b + sum_r (A_r x)@W_r );  block = 64 dst rows, 4 waves.

template <int DOUT, bool LSM>
__launch_bounds__(256)
__global__ void fused_layer(const unsigned short* __restrict__ xb,  // [N][128] bf16
                            const unsigned short* __restrict__ wt,  // [9][DOUT][128] bf16
                            const int* __restrict__ boffs,          // [8*NT+1]
                            const int* __restrict__ packed,         // [E] row<<20|src
                            const float* __restrict__ bias,         // [DOUT]
                            unsigned short* __restrict__ out_b,
                            float* __restrict__ out_f,
                            int N, int NT) {
  __shared__ float yl[64 * 132];     // fp32 aggregation tile, padded stride

  int tid = threadIdx.x, wid = tid >> 6, lane = tid & 63;
  int colb = lane & 15, kgrp = lane >> 4;
  int tile = blockIdx.x, tilebase = tile * 64;

  f32x4 acc[DOUT / 16];
#pragma unroll
  for (int nf = 0; nf < DOUT / 16; ++nf) {
    f32x4 z = {0.f, 0.f, 0.f, 0.f};
    acc[nf] = z;
  }

  // ---- root transform: A rows from global x, B from wt[8] ----
  {
    const unsigned short* wr = wt + (size_t)8 * DOUT * 128;
    int ra = tilebase + wid * 16 + colb;
    const unsigned short* pa = xb + (size_t)(ra < N ? ra : 0) * 128;
#pragma unroll
    for (int kk = 0; kk < 4; ++kk) {
      int kbase = kk * 32 + kgrp * 8;
      bf16x8 a0 = *(const bf16x8*)(pa + kbase);
#pragma unroll
      for (int nf = 0; nf < DOUT / 16; ++nf) {
        bf16x8 b = *(const bf16x8*)(wr + (size_t)(nf * 16 + colb) * 128 + kbase);
        acc[nf] = __builtin_amdgcn_mfma_f32_16x16x32_bf16(a0, b, acc[nf], 0, 0, 0);
      }
    }
  }

  // ---- 8 relations: edge-parallel aggregate into LDS fp32, then MFMA ----
  for (int r = 0; r < 8; ++r) {
    __syncthreads();   // prev MFMA reads of yl complete
#pragma unroll 4
    for (int i = tid; i < 64 * 132 / 4; i += 256) {
      f32x4 z = {0.f, 0.f, 0.f, 0.f};
      ((f32x4*)yl)[i] = z;
    }
    __syncthreads();

    int bkt = r * NT + tile;
    int lo = boffs[bkt], hi = boffs[bkt + 1];
    // quarter-wave per edge: 16 lanes read one 256B row, LDS-atomic accumulate
    for (int i = lo + wid * 4 + kgrp; i < hi; i += 16) {
      int pk = packed[i];
      int src = pk & 0xFFFFF;
      int row = pk >> 20;
      bf16x8 v = *(const bf16x8*)(xb + (size_t)src * 128 + colb * 8);
      float* yr = yl + row * 132 + colb * 8;
#pragma unroll
      for (int c = 0; c < 8; ++c)
        atomicAdd(&yr[c], b2f((unsigned short)v[c]));
    }
    __syncthreads();

    const unsigned short* wr = wt + (size_t)r * DOUT * 128;
    int arow = wid * 16 + colb;
#pragma unroll
    for (int kk = 0; kk < 4; ++kk) {
      int kbase = kk * 32 + kgrp * 8;
      f32x4 p0 = *(const f32x4*)(yl + arow * 132 + kbase);
      f32x4 p1 = *(const f32x4*)(yl + arow * 132 + kbase + 4);
      bf16x8 a;
#pragma unroll
      for (int j = 0; j < 4; ++j) {
        a[j] = (short)f2b(p0[j]);
        a[4 + j] = (short)f2b(p1[j]);
      }
#pragma unroll
      for (int nf = 0; nf < DOUT / 16; ++nf) {
        bf16x8 b = *(const bf16x8*)(wr + (size_t)(nf * 16 + colb) * 128 + kbase);
        acc[nf] = __builtin_amdgcn_mfma_f32_16x16x32_bf16(a, b, acc[nf], 0, 0, 0);
      }
    }
  }

  // ---- epilogue ----
  float bv[DOUT / 16];
#pragma unroll
  for (int nf = 0; nf < DOUT / 16; ++nf) bv[nf] = bias[nf * 16 + colb];

#pragma unroll
  for (int i = 0; i < 4; ++i) {
    int row = tilebase + wid * 16 + kgrp * 4 + i;
    if (row >= N) continue;
    if (!LSM) {
#pragma unroll
      for (int nf = 0; nf < DOUT / 16; ++nf) {
        float v = acc[nf][i] + bv[nf];
        out_b[(size_t)row * DOUT + nf * 16 + colb] = f2b(fmaxf(v, 0.f));
      }
    } else {
      // DOUT==64: row's 64 cols live in this 16-lane group (colb) x 4 nf
      float v[4];
#pragma unroll
      for (int nf = 0; nf < 4; ++nf) v[nf] = acc[nf][i] + bv[nf];
      float m = fmaxf(fmaxf(v[0], v[1]), fmaxf(v[2], v[3]));
#pragma unroll
      for (int s = 1; s < 16; s <<= 1) m = fmaxf(m, __shfl_xor(m, s));
      float sum = 0.f;
#pragma unroll
      for (int nf = 0; nf < 4; ++nf) sum += __expf(v[nf] - m);
#pragma unroll
      for (int s = 1; s < 16; s <<= 1) sum += __shfl_xor(sum, s);
      float lse = m + __logf(sum);
#pragma unroll
      for (int nf = 0; nf < 4; ++nf)
        out_f[(size_t)row * 64 + nf * 16 + colb] = v[nf] - lse;
    }
  }
}

// ---------------- input cast ----------------

__global__ void cast_kernel(const float* __restrict__ in, unsigned short* __restrict__ out,
                            int n4) {
  int stride = gridDim.x * blockDim.x;
  for (int i = blockIdx.x * blockDim.x + threadIdx.x; i < n4; i += stride) {
    float4 v = ((const float4*)in)[i];
    ushort4 o;
    o.x = f2b(v.x); o.y = f2b(v.y); o.z = f2b(v.z); o.w = f2b(v.w);
    ((ushort4*)out)[i] = o;
  }
}

// ---------------- launch ----------------

extern "C" void kernel_launch(void* const* d_in, const int* in_sizes, int n_in,
                              void* d_out, int out_size, void* d_ws, size_t ws_size,
                              hipStream_t stream) {
  const float* x = (const float*)d_in[0];
  const int* eidx = (const int*)d_in[1];     // int32
  const int* et = (const int*)d_in[2];       // int32
  const float* Wrel1 = (const float*)d_in[3];
  const float* Wroot1 = (const float*)d_in[4];
  const float* b1 = (const float*)d_in[5];
  const float* Wrel2 = (const float*)d_in[6];
  const float* Wroot2 = (const float*)d_in[7];
  const float* b2 = (const float*)d_in[8];
  const float* Wrel3 = (const float*)d_in[9];
  const float* Wroot3 = (const float*)d_in[10];
  const float* b3 = (const float*)d_in[11];

  const int N = in_sizes[0] / 128;    // 100000
  const int E = in_sizes[2];          // 1600000
  const int NT = (N + 63) / 64;       // 1563 dst tiles
  const int NB = 8 * NT;              // 12504 buckets
  const int* esrc = eidx;
  const int* edst = eidx + E;

  char* p = (char*)d_ws;
  auto carve = [&](size_t bytes) {
    void* q = (void*)p;
    p += (bytes + 255) & ~(size_t)255;
    return q;
  };
  unsigned short* bufX0 = (unsigned short*)carve((size_t)N * 128 * 2);
  unsigned short* bufX1 = (unsigned short*)carve((size_t)N * 128 * 2);
  unsigned short* wt1 = (unsigned short*)carve((size_t)9 * 128 * 128 * 2);
  unsigned short* wt2 = (unsigned short*)carve((size_t)9 * 128 * 128 * 2);
  unsigned short* wt3 = (unsigned short*)carve((size_t)9 * 64 * 128 * 2);
  int* packed = (int*)carve((size_t)E * 4);
  int* cnt = (int*)carve((size_t)NB * 4);
  int* offs = (int*)carve((size_t)(NB + 1) * 4);
  int* cursor = (int*)carve((size_t)NB * 4);
  const int nbs = (NB + 255) / 256;
  int* bsum = (int*)carve((size_t)nbs * 4);

  // ---- bucket sort (once; reused by all 3 layers) ----
  k_zero2<<<64, 256, 0, stream>>>(cnt, NB);
  k_hist2<<<2048, 256, 0, stream>>>(et, edst, cnt, NT, E);
  k_scan1<<<nbs, 256, 0, stream>>>(cnt, offs, bsum, NB);
  k_scan2<<<1, 256, 0, stream>>>(bsum, nbs);
  k_scan3<<<nbs, 256, 0, stream>>>(offs, bsum, cursor, NB, E);
  k_fill2<<<2048, 256, 0, stream>>>(et, esrc, edst, cursor, packed, NT, E);

  // ---- weight prep + input cast ----
  wprep_kernel<<<576, 256, 0, stream>>>(Wrel1, Wroot1, wt1, 128);
  wprep_kernel<<<576, 256, 0, stream>>>(Wrel2, Wroot2, wt2, 128);
  wprep_kernel<<<288, 256, 0, stream>>>(Wrel3, Wroot3, wt3, 64);
  cast_kernel<<<2048, 256, 0, stream>>>(x, bufX0, N * 128 / 4);

  fused_layer<128, false><<<NT, 256, 0, stream>>>(bufX0, wt1, offs, packed, b1, bufX1, (float*)nullptr, N, NT);
  fused_layer<128, false><<<NT, 256, 0, stream>>>(bufX1, wt2, offs, packed, b2, bufX0, (float*)nullptr, N, NT);
  fused_layer<64, true><<<NT, 256, 0, stream>>>(bufX0, wt3, offs, packed, b3, (unsigned short*)nullptr, (float*)d_out, N, NT);
}